// Round 6
// baseline (171.908 us; speedup 1.0000x reference)
//
#include <hip/hip_runtime.h>

// ScaledDotProductAttention w/ ALiBi + key padding mask. B=1,H=16,S=2048,D=64 fp32.
// R12: SINGLE fused kernel. Preprocess deleted — each chunk block converts its
// own <=4 fp32 K/V tiles to swizzled bf16 directly in LDS (T14: next tile's
// fp32 loads issued before compute, convert+ds_write after the read barrier).
// Bias computed per-block into LDS. Tickets zeroed by hipMemsetAsync.
// Carried (R9): fused combine via device-coherent sc0/sc1 partials + ticket.
// Carried (R6): weighted per-head chunking (<=4 tiles/block), direct O-write
// for 1-chunk heads, mask sniff, no online max (bias in acc init, exp2-domain),
// ALiBi window cut, swizzled bf16 K/V^T in LDS, packed-u32 P round-trip.

constexpr int   S_LEN  = 2048;
constexpr int   D_DIM  = 64;
constexpr int   H_NUM  = 16;
constexpr int   QT     = 128;            // q rows per block (4 waves x 32)
constexpr int   K_TILE = 64;
constexpr int   NTILE  = S_LEN / K_TILE; // 32
constexpr int   MAXNC  = 8;              // max chunks per head (z-dim)
constexpr int   QB     = S_LEN / QT;     // 16
constexpr int   PROWSTR= 36;             // dwords per P row (144B, 16B-mult)
constexpr float SCL    = 0.18033688f;    // 0.125 * log2(e)
constexpr float L2E    = 1.44269504f;
constexpr float MASKED = -50000.0f;      // exp2-domain masked-key sentinel -> exp2 = 0
constexpr float CUTOFF = 40.0f;          // log2-units: bias < -40 => key negligible

typedef short bf16x8 __attribute__((ext_vector_type(8)));
typedef short bf16x4 __attribute__((ext_vector_type(4)));
typedef float f32x4  __attribute__((ext_vector_type(4)));

__device__ inline short f2bf(float f) {
    union { float f; unsigned u; } x; x.f = f;
    return (short)((x.u + 0x7fffu + ((x.u >> 16) & 1u)) >> 16);  // RNE
}

__device__ inline unsigned pack2bf(float a, float b) {
#if __has_builtin(__builtin_amdgcn_cvt_pk_bf16_f32)
    auto p = __builtin_amdgcn_cvt_pk_bf16_f32(a, b);
    unsigned u; __builtin_memcpy(&u, &p, 4); return u;
#else
    return (unsigned)(unsigned short)f2bf(a) | ((unsigned)(unsigned short)f2bf(b) << 16);
#endif
}

__device__ inline float fexp2(float x) {
#if __has_builtin(__builtin_amdgcn_exp2f)
    return __builtin_amdgcn_exp2f(x);
#else
    return exp2f(x);
#endif
}

__device__ inline unsigned permb(unsigned hi, unsigned lo, unsigned sel) {
#if __has_builtin(__builtin_amdgcn_perm)
    return __builtin_amdgcn_perm(hi, lo, sel);
#else
    return (sel == 0x05040100u) ? ((lo & 0xffffu) | (hi << 16))
                                : ((lo >> 16) | (hi & 0xffff0000u));
#endif
}

// device-coherent (agent-scope) 16B store/load: sc0 sc1 write-through/bypass of
// the non-coherent per-XCD L2 -> no bulk wbl2/inv fences needed for visibility.
__device__ inline void store4_sc(float* p, f32x4 v) {
    asm volatile("global_store_dwordx4 %0, %1, off sc0 sc1"
                 :: "v"(p), "v"(v) : "memory");
}
__device__ inline f32x4 load4_sc(const float* p) {
    f32x4 v;
    asm volatile("global_load_dwordx4 %0, %1, off sc0 sc1"
                 : "=v"(v) : "v"(p) : "memory");
    return v;   // caller must s_waitcnt vmcnt(0) before use
}

// first live tile for head h
__device__ inline int head_t0(int h) {
    const float slope_l2e = exp2f(-0.5f * (float)(h + 1)) * L2E;
    const float kmin = 2047.0f - CUTOFF / slope_l2e;
    return kmin <= 0.0f ? 0 : ((int)kmin) >> 6;
}
// chunks for head h: ceil(live_tiles / 4), capped at MAXNC
__device__ inline int head_nc(int h) {
    const int nt = NTILE - head_t0(h);
    const int nc = (nt + 3) >> 2;
    return nc > MAXNC ? MAXNC : nc;
}

// ---- the one kernel: per-chunk flash with in-block K/V conversion and
//      fused last-arriver combine ----
__global__ __launch_bounds__(256, 4)
void attn_all(const float* __restrict__ Qm, const float* __restrict__ Km,
              const float* __restrict__ Vm, const void* __restrict__ maskp,
              float* __restrict__ Om, float* __restrict__ Opart,
              float* __restrict__ lp, unsigned* __restrict__ Tickets)
{
    __shared__ short    k_lds[4096];
    __shared__ short    v_lds[4096];
    __shared__ float    bias_lds[256];        // up to 4 tiles x 64 keys
    __shared__ unsigned p_lds[4][32 * PROWSTR];
    __shared__ int      is_last;
    __shared__ int      mask_is_i32;

    const int tid = threadIdx.x;
    const int wave = tid >> 6, lane = tid & 63;
    const int l16 = lane & 15, quad = lane >> 4;
    const int h = blockIdx.y, qblk = blockIdx.x, c = blockIdx.z;

    const int nc = head_nc(h);
    if (c >= nc) return;                      // dead chunk for this head
    const int t0 = head_t0(h);
    const int nt = NTILE - t0;
    const int tstart = t0 + (c * nt) / nc;
    const int tend   = t0 + ((c + 1) * nt) / nc;   // <= tstart+4

    // per-thread conversion coordinates (same mapping as the old preprocess)
    const int key0 = tid >> 3, c0 = tid & 7;  // K pass it=0; it=1 is key0+32
    const int db = tid >> 4, kb = tid & 15;
    const int d4 = db * 4, key4 = kb * 4;

    const size_t hbase = (size_t)h * S_LEN * D_DIM;

    // mask-dtype sniff: first wave, one load + ballot
    if (tid < 64) {
        const unsigned v = ((const unsigned*)maskp)[tid];
        const unsigned long long b = __ballot(v <= 1u);
        if (tid == 0) mask_is_i32 = (b == ~0ULL);
    }

    // T14 staging registers (static names, fully unrolled accesses)
    float4 kr0, kr1, kr2, kr3, vr0, vr1, vr2, vr3;

    #define STAGE_LOAD(KT)                                                     \
    do {                                                                       \
        const float* tbK = Km + hbase + (size_t)(KT) * K_TILE * D_DIM;         \
        const float* s0 = tbK + key0 * 64 + c0 * 8;                            \
        kr0 = *(const float4*)s0;  kr1 = *(const float4*)(s0 + 4);             \
        const float* s1 = tbK + (key0 + 32) * 64 + c0 * 8;                     \
        kr2 = *(const float4*)s1;  kr3 = *(const float4*)(s1 + 4);             \
        const float* tbV = Vm + hbase + (size_t)(KT) * K_TILE * D_DIM;         \
        vr0 = *(const float4*)(tbV + (key4 + 0) * 64 + d4);                    \
        vr1 = *(const float4*)(tbV + (key4 + 1) * 64 + d4);                    \
        vr2 = *(const float4*)(tbV + (key4 + 2) * 64 + d4);                    \
        vr3 = *(const float4*)(tbV + (key4 + 3) * 64 + d4);                    \
    } while (0)

    #define STAGE_WRITE()                                                      \
    do {                                                                       \
        unsigned ua[4] = { pack2bf(kr0.x, kr0.y), pack2bf(kr0.z, kr0.w),       \
                           pack2bf(kr1.x, kr1.y), pack2bf(kr1.z, kr1.w) };     \
        bf16x8 kpa; __builtin_memcpy(&kpa, ua, 16);                            \
        *(bf16x8*)&k_lds[key0 * 64 + ((c0 ^ (key0 & 7)) << 3)] = kpa;          \
        unsigned ub[4] = { pack2bf(kr2.x, kr2.y), pack2bf(kr2.z, kr2.w),       \
                           pack2bf(kr3.x, kr3.y), pack2bf(kr3.z, kr3.w) };     \
        bf16x8 kpb; __builtin_memcpy(&kpb, ub, 16);                            \
        const int key1 = key0 + 32;                                           \
        *(bf16x8*)&k_lds[key1 * 64 + ((c0 ^ (key1 & 7)) << 3)] = kpb;          \
        const float* vp0 = (const float*)&vr0;                                 \
        const float* vp1 = (const float*)&vr1;                                 \
        const float* vp2 = (const float*)&vr2;                                 \
        const float* vp3 = (const float*)&vr3;                                 \
        _Pragma("unroll")                                                      \
        for (int jj = 0; jj < 4; ++jj) {                                       \
            const int d = d4 + jj;                                             \
            bf16x4 ov;                                                         \
            ov[0] = f2bf(vp0[jj]); ov[1] = f2bf(vp1[jj]);                      \
            ov[2] = f2bf(vp2[jj]); ov[3] = f2bf(vp3[jj]);                      \
            *(bf16x4*)&v_lds[d * 64 + (((key4 >> 3) ^ (d & 7)) << 3) + (key4 & 7)] = ov; \
        }                                                                      \
    } while (0)

    // issue first tile's fp32 loads early
    STAGE_LOAD(tstart);

    // Q A-frags for 2 strips, scaled by 0.125*log2(e)
    bf16x8 qfrag[2][2];
    {
        const float* Qh = Qm + hbase;
        #pragma unroll
        for (int s = 0; s < 2; ++s) {
            const int qrow = qblk * QT + wave * 32 + s * 16 + l16;
            #pragma unroll
            for (int t = 0; t < 2; ++t) {
                const float* src = Qh + (size_t)qrow * D_DIM + t * 32 + quad * 8;
                float4 a = *(const float4*)src;
                float4 b = *(const float4*)(src + 4);
                unsigned* qp = (unsigned*)&qfrag[s][t];
                qp[0] = pack2bf(a.x * SCL, a.y * SCL);
                qp[1] = pack2bf(a.z * SCL, a.w * SCL);
                qp[2] = pack2bf(b.x * SCL, b.y * SCL);
                qp[3] = pack2bf(b.z * SCL, b.w * SCL);
            }
        }
    }

    bf16x8 onesv;
    #pragma unroll
    for (int i = 0; i < 8; ++i) onesv[i] = (short)0x3F80;  // bf16 1.0

    f32x4 o_frag[2][4], l4[2];
    #pragma unroll
    for (int s = 0; s < 2; ++s) {
        #pragma unroll
        for (int cc = 0; cc < 4; ++cc) o_frag[s][cc] = (f32x4){0.f, 0.f, 0.f, 0.f};
        l4[s] = (f32x4){0.f, 0.f, 0.f, 0.f};
    }

    __syncthreads();                          // mask_is_i32 visible

    // bias for this block's tiles (exp2 units, mask folded): 1 value/thread
    {
        const int tt = tid >> 6, kk = tid & 63;
        if (tstart + tt < tend) {
            const int key = (tstart + tt) * K_TILE + kk;
            const int mv = mask_is_i32 ? ((const int*)maskp)[key]
                                       : (int)((const unsigned char*)maskp)[key];
            const float slope_l2e = exp2f(-0.5f * (float)(h + 1)) * L2E;
            bias_lds[tid] = mv ? slope_l2e * (float)(key - (S_LEN - 1)) : MASKED;
        }
    }

    STAGE_WRITE();                            // first tile: convert + LDS write
    __syncthreads();                          // tile + bias ready for all waves

    const unsigned psel = (quad < 2) ? 0x05040100u : 0x07060302u;
    unsigned* pw = p_lds[wave];
    const int swz = l16 & 7;

    for (int kt = tstart; kt < tend; ++kt) {
        const bool pre = (kt + 1 < tend);     // block-uniform
        if (pre) STAGE_LOAD(kt + 1);          // T14 issue-early
        __builtin_amdgcn_sched_barrier(0);    // pin issue above compute

        const float* bm = &bias_lds[(kt - tstart) * K_TILE];

        // S(+bias) = bias_init + Q K^T
        f32x4 sv[2][4];
        __builtin_amdgcn_s_setprio(1);
        #pragma unroll
        for (int cc = 0; cc < 4; ++cc) {
            const float b = bm[cc * 16 + l16];
            const f32x4 binit = (f32x4){b, b, b, b};
            sv[0][cc] = binit;
            sv[1][cc] = binit;
            #pragma unroll
            for (int t = 0; t < 2; ++t) {
                bf16x8 bfrag = *(const bf16x8*)&k_lds[(cc * 16 + l16) * 64 + (((t * 4 + quad) ^ swz) << 3)];
                sv[0][cc] = __builtin_amdgcn_mfma_f32_16x16x32_bf16(qfrag[0][t], bfrag, sv[0][cc], 0, 0, 0);
                sv[1][cc] = __builtin_amdgcn_mfma_f32_16x16x32_bf16(qfrag[1][t], bfrag, sv[1][cc], 0, 0, 0);
            }
        }
        __builtin_amdgcn_s_setprio(0);

        // p = exp2(s)
        #pragma unroll
        for (int s = 0; s < 2; ++s) {
            #pragma unroll
            for (int r = 0; r < 4; ++r) {
                const float p0 = fexp2(sv[s][0][r]);
                const float p1 = fexp2(sv[s][1][r]);
                const float p2 = fexp2(sv[s][2][r]);
                const float p3 = fexp2(sv[s][3][r]);
                unsigned* pp = &pw[(s * 16 + quad * 4 + r) * PROWSTR + l16];
                pp[0]  = pack2bf(p0, p1);
                pp[16] = pack2bf(p2, p3);
            }
        }

        // O += P V ; l += P * ones
        #pragma unroll
        for (int t2 = 0; t2 < 2; ++t2) {
            bf16x8 pfrag[2];
            #pragma unroll
            for (int s = 0; s < 2; ++s) {
                const unsigned* pr = &pw[(s * 16 + l16) * PROWSTR + t2 * 16 + (quad & 1) * 8];
                uint4 w0 = *(const uint4*)(pr);
                uint4 w1 = *(const uint4*)(pr + 4);
                unsigned pf[4];
                pf[0] = permb(w0.y, w0.x, psel);
                pf[1] = permb(w0.w, w0.z, psel);
                pf[2] = permb(w1.y, w1.x, psel);
                pf[3] = permb(w1.w, w1.z, psel);
                __builtin_memcpy(&pfrag[s], pf, 16);
            }
            __builtin_amdgcn_s_setprio(1);
            #pragma unroll
            for (int c2 = 0; c2 < 4; ++c2) {
                bf16x8 vfrag = *(const bf16x8*)&v_lds[(c2 * 16 + l16) * 64 + (((t2 * 4 + quad) ^ swz) << 3)];
                o_frag[0][c2] = __builtin_amdgcn_mfma_f32_16x16x32_bf16(pfrag[0], vfrag, o_frag[0][c2], 0, 0, 0);
                o_frag[1][c2] = __builtin_amdgcn_mfma_f32_16x16x32_bf16(pfrag[1], vfrag, o_frag[1][c2], 0, 0, 0);
            }
            l4[0] = __builtin_amdgcn_mfma_f32_16x16x32_bf16(pfrag[0], onesv, l4[0], 0, 0, 0);
            l4[1] = __builtin_amdgcn_mfma_f32_16x16x32_bf16(pfrag[1], onesv, l4[1], 0, 0, 0);
            __builtin_amdgcn_s_setprio(0);
        }

        if (pre) {
            __syncthreads();                  // all waves done reading k/v_lds
            STAGE_WRITE();                    // convert + write next tile
            __syncthreads();                  // visible to all waves
        }
    }

    if (nc == 1) {
        // sole chunk: write normalized O directly, skip combine
        float* Oh = Om + hbase;
        const int qrow0 = qblk * QT + wave * 32;
        #pragma unroll
        for (int s = 0; s < 2; ++s) {
            #pragma unroll
            for (int r = 0; r < 4; ++r) {
                const float inv = 1.0f / l4[s][r];
                const int row = qrow0 + s * 16 + quad * 4 + r;
                float* dst = Oh + (size_t)row * D_DIM + l16;
                dst[0]  = o_frag[s][0][r] * inv;
                dst[16] = o_frag[s][1][r] * inv;
                dst[32] = o_frag[s][2][r] * inv;
                dst[48] = o_frag[s][3][r] * inv;
            }
        }
    } else {
        // r-packed partial + l per row-group; slot = h*MAXNC + c.
        // Device-coherent (sc0 sc1) stores: no bulk L2 writeback fence needed.
        #pragma unroll
        for (int s = 0; s < 2; ++s) {
            const int g = qblk * 32 + wave * 8 + s * 4 + quad;
            const size_t gbase = (((size_t)h * MAXNC + c) * 512 + g);
            #pragma unroll
            for (int c2 = 0; c2 < 4; ++c2)
                store4_sc(Opart + (gbase * 64 + c2 * 16 + l16) * 4, o_frag[s][c2]);
            if (l16 == 0) store4_sc(lp + gbase * 4, l4[s]);
        }

        // drain our coherent stores, then take a ticket; last arriver combines.
        asm volatile("s_waitcnt vmcnt(0)" ::: "memory");
        __syncthreads();
        if (tid == 0) {
            const unsigned old = atomicAdd(&Tickets[h * QB + qblk], 1u);
            is_last = (old == (unsigned)(nc - 1)) ? 1 : 0;
        }
        __syncthreads();
        if (is_last) {
            // peers' partials reached the device coherence point before their
            // ticket increments; read with sc1 loads (bypass stale L1/L2).
            for (int cc2 = 0; cc2 < nc; ++cc2) {
                if (cc2 == c) continue;   // own chunk already in registers
                f32x4 t[2][4], tl[2];
                #pragma unroll
                for (int s = 0; s < 2; ++s) {
                    const int g = qblk * 32 + wave * 8 + s * 4 + quad;
                    const size_t gbase = (((size_t)h * MAXNC + cc2) * 512 + g);
                    tl[s] = load4_sc(lp + gbase * 4);
                    #pragma unroll
                    for (int c2 = 0; c2 < 4; ++c2)
                        t[s][c2] = load4_sc(Opart + (gbase * 64 + c2 * 16 + l16) * 4);
                }
                asm volatile("s_waitcnt vmcnt(0)" ::: "memory");
                __builtin_amdgcn_sched_barrier(0);  // rule #18 guard
                #pragma unroll
                for (int s = 0; s < 2; ++s) {
                    l4[s] += tl[s];
                    #pragma unroll
                    for (int c2 = 0; c2 < 4; ++c2) o_frag[s][c2] += t[s][c2];
                }
            }
            // normalized write (same mapping as the nc==1 path)
            float* Oh = Om + hbase;
            const int qrow0 = qblk * QT + wave * 32;
            #pragma unroll
            for (int s = 0; s < 2; ++s) {
                #pragma unroll
                for (int r = 0; r < 4; ++r) {
                    const float inv = 1.0f / l4[s][r];
                    const int row = qrow0 + s * 16 + quad * 4 + r;
                    float* dst = Oh + (size_t)row * D_DIM + l16;
                    dst[0]  = o_frag[s][0][r] * inv;
                    dst[16] = o_frag[s][1][r] * inv;
                    dst[32] = o_frag[s][2][r] * inv;
                    dst[48] = o_frag[s][3][r] * inv;
                }
            }
        }
    }
    #undef STAGE_LOAD
    #undef STAGE_WRITE
}

extern "C" void kernel_launch(void* const* d_in, const int* in_sizes, int n_in,
                              void* d_out, int out_size, void* d_ws, size_t ws_size,
                              hipStream_t stream) {
    (void)in_sizes; (void)n_in; (void)out_size; (void)ws_size;
    const float* Q = (const float*)d_in[0];
    const float* K = (const float*)d_in[1];
    const float* V = (const float*)d_in[2];
    const void*  M = d_in[3];
    float* O = (float*)d_out;

    char* ws = (char*)d_ws;
    size_t off = 0;
    float* Opart = (float*)(ws + off); off += (size_t)H_NUM * MAXNC * 512 * 64 * 4 * 4;    // 64 MB
    float* lp    = (float*)(ws + off); off += (size_t)H_NUM * MAXNC * 512 * 4 * 4;         // 1 MB
    unsigned* Tickets = (unsigned*)(ws + off); off += (size_t)H_NUM * QB * 4;              // 1 KB

    hipMemsetAsync(Tickets, 0, (size_t)H_NUM * QB * 4, stream);
    attn_all<<<dim3(QB, H_NUM, MAXNC), 256, 0, stream>>>(Q, K, V, M, O, Opart, lp, Tickets);
}

// Round 7
// 101.361 us; speedup vs baseline: 1.6960x; 1.6960x over previous
//
#include <hip/hip_runtime.h>

// ScaledDotProductAttention w/ ALiBi + key padding mask. B=1,H=16,S=2048,D=64 fp32.
// R13: pair-merged chunks — 512-thread main blocks (8 waves = 4 q-strips x
// 2 chunk-groups, each group <=4 tiles = R6 makespan). Groups merge (O,l) in
// LDS; heads with nt<=8 write O directly. Partial-writing blocks 880 -> 432,
// halving combine traffic. Plain stores + kernel-boundary coherence (R12
// showed sc0/sc1 write-through costs ~8x HBM write amplification; R7 showed
// __threadfence costs ~120us).
// Carried (R6): compact bf16 swizzled K/V^T intermediate (R12 showed fp32
// re-read from poison-cold L3 costs 156MB fetch), weighted chunking, mask
// sniff, no online max (bias in acc init, exp2-domain), ALiBi window cut,
// packed-u32 P round-trip, setprio.

constexpr int   S_LEN  = 2048;
constexpr int   D_DIM  = 64;
constexpr int   H_NUM  = 16;
constexpr int   QT     = 128;            // q rows per block (4 strips x 32)
constexpr int   K_TILE = 64;
constexpr int   NTILE  = S_LEN / K_TILE; // 32
constexpr int   NPMAX  = 4;              // max pair-chunks per head (z-dim)
constexpr int   QB     = S_LEN / QT;     // 16
constexpr int   PROWSTR= 36;             // dwords per P row (144B, 16B-mult)
constexpr float SCL    = 0.18033688f;    // 0.125 * log2(e)
constexpr float L2E    = 1.44269504f;
constexpr float MASKED = -50000.0f;      // exp2-domain masked-key sentinel -> exp2 = 0
constexpr float CUTOFF = 40.0f;          // log2-units: bias < -40 => key negligible

typedef short bf16x8 __attribute__((ext_vector_type(8)));
typedef short bf16x4 __attribute__((ext_vector_type(4)));
typedef float f32x4  __attribute__((ext_vector_type(4)));

__device__ inline short f2bf(float f) {
    union { float f; unsigned u; } x; x.f = f;
    return (short)((x.u + 0x7fffu + ((x.u >> 16) & 1u)) >> 16);  // RNE
}

__device__ inline unsigned pack2bf(float a, float b) {
#if __has_builtin(__builtin_amdgcn_cvt_pk_bf16_f32)
    auto p = __builtin_amdgcn_cvt_pk_bf16_f32(a, b);
    unsigned u; __builtin_memcpy(&u, &p, 4); return u;
#else
    return (unsigned)(unsigned short)f2bf(a) | ((unsigned)(unsigned short)f2bf(b) << 16);
#endif
}

__device__ inline float fexp2(float x) {
#if __has_builtin(__builtin_amdgcn_exp2f)
    return __builtin_amdgcn_exp2f(x);
#else
    return exp2f(x);
#endif
}

__device__ inline unsigned permb(unsigned hi, unsigned lo, unsigned sel) {
#if __has_builtin(__builtin_amdgcn_perm)
    return __builtin_amdgcn_perm(hi, lo, sel);
#else
    return (sel == 0x05040100u) ? ((lo & 0xffffu) | (hi << 16))
                                : ((lo >> 16) | (hi & 0xffff0000u));
#endif
}

__device__ inline void load_lds16(const void* g, void* l) {
    __builtin_amdgcn_global_load_lds((const __attribute__((address_space(1))) void*)g,
                                     (__attribute__((address_space(3))) void*)l, 16, 0, 0);
}

// first live tile for head h (identical IEEE expression in all kernels)
__device__ inline int head_t0(int h) {
    const float slope_l2e = exp2f(-0.5f * (float)(h + 1)) * L2E;
    const float kmin = 2047.0f - CUTOFF / slope_l2e;
    return kmin <= 0.0f ? 0 : ((int)kmin) >> 6;
}
// pair-chunks for head h: ceil(live_tiles / 8), capped at NPMAX
__device__ inline int head_np(int h) {
    const int nt = NTILE - head_t0(h);
    const int np = (nt + 7) >> 3;
    return np > NPMAX ? NPMAX : np;
}

// ---- preprocess: K -> bf16 row-chunk-swizzled, V -> bf16 transposed+swizzled,
//      bias (exp2 units, mask folded). Only live tiles. ----
__global__ __launch_bounds__(256)
void preprocess_kernel(const float* __restrict__ Km, const float* __restrict__ Vm,
                       const void* __restrict__ maskp,
                       short* __restrict__ Kswz, short* __restrict__ Vswz,
                       float* __restrict__ Bias)
{
    __shared__ int mask_is_i32;
    const int tid = threadIdx.x;
    const int kt = blockIdx.x, h = blockIdx.y;
    if (kt < head_t0(h)) return;            // dead tile for this head

    const int kbase = kt * K_TILE;
    const size_t tbase = ((size_t)h * S_LEN + kbase) * D_DIM;
    short* Kd = Kswz + ((size_t)h * NTILE + kt) * 4096;
    short* Vd = Vswz + ((size_t)h * NTILE + kt) * 4096;

    // parallel mask-dtype sniff: first wave, one load + ballot
    if (tid < 64) {
        const unsigned v = ((const unsigned*)maskp)[tid];
        const unsigned long long b = __ballot(v <= 1u);
        if (tid == 0) mask_is_i32 = (b == ~0ULL);
    }

    // K: chunk c of row `key` stored at c ^ (key&7)
    #pragma unroll
    for (int it = 0; it < 2; ++it) {
        const int idx = it * 256 + tid;
        const int key = idx >> 3, c = idx & 7;
        const float* src = Km + tbase + key * 64 + c * 8;
        float4 a = *(const float4*)src;
        float4 b = *(const float4*)(src + 4);
        unsigned u[4] = { pack2bf(a.x, a.y), pack2bf(a.z, a.w),
                          pack2bf(b.x, b.y), pack2bf(b.z, b.w) };
        bf16x8 kp; __builtin_memcpy(&kp, u, 16);
        *(bf16x8*)(Kd + key * 64 + ((c ^ (key & 7)) << 3)) = kp;
    }

    // V: 4x4 register transpose; row d, key-chunk (key>>3)^(d&7)
    {
        const int db = tid >> 4, kb = tid & 15;
        const int d4 = db * 4, key4 = kb * 4;
        float4 vv[4];
        #pragma unroll
        for (int j = 0; j < 4; ++j)
            vv[j] = *(const float4*)(Vm + tbase + (key4 + j) * 64 + d4);
        const float* vp = (const float*)vv;
        #pragma unroll
        for (int jj = 0; jj < 4; ++jj) {
            const int d = d4 + jj;
            bf16x4 ov;
            ov[0] = f2bf(vp[0 * 4 + jj]); ov[1] = f2bf(vp[1 * 4 + jj]);
            ov[2] = f2bf(vp[2 * 4 + jj]); ov[3] = f2bf(vp[3 * 4 + jj]);
            *(bf16x4*)(Vd + d * 64 + (((key4 >> 3) ^ (d & 7)) << 3) + (key4 & 7)) = ov;
        }
    }
    __syncthreads();
    if (tid < K_TILE) {
        const int key = kbase + tid;
        const int mv = mask_is_i32 ? ((const int*)maskp)[key]
                                   : (int)((const unsigned char*)maskp)[key];
        const float slope_l2e = exp2f(-0.5f * (float)(h + 1)) * L2E;
        Bias[h * S_LEN + key] = mv ? slope_l2e * (float)(key - (S_LEN - 1)) : MASKED;
    }
}

// ---- main flash kernel: 8 waves = 4 q-strips x 2 chunk-groups (each <=4
//      tiles); LDS merge of the two groups; direct O write when np==1,
//      else plain-store partials for the combine kernel. ----
__global__ __launch_bounds__(512, 2)
void attn_main(const float* __restrict__ Qm, const short* __restrict__ Kswz,
               const short* __restrict__ Vswz, const float* __restrict__ Bias,
               float* __restrict__ Om, float* __restrict__ Opart,
               float* __restrict__ lp)
{
    __shared__ short    k_lds[2][4096];      // per chunk-group 64x64 bf16
    __shared__ short    v_lds[2][4096];
    __shared__ float    bias_lds[512];       // up to 8 tiles x 64 keys
    __shared__ unsigned p_lds[8][32 * PROWSTR];  // 36.9 KB; reused as cb
    __shared__ float    l_cb[4][32];

    const int tid = threadIdx.x;
    const int wave = tid >> 6, lane = tid & 63;
    const int l16 = lane & 15, quad = lane >> 4;
    const int sw = wave & 3;                 // q-strip (32 rows)
    const int cw = wave >> 2;                // chunk-group
    const int h = blockIdx.y, qblk = blockIdx.x, p = blockIdx.z;

    const int np = head_np(h);
    if (p >= np) return;                     // dead pair for this head
    const int t0 = head_t0(h);
    const int nt = NTILE - t0;
    const int tstart = t0 + (p * nt) / np;
    const int tend   = t0 + ((p + 1) * nt) / np;   // <= tstart+8
    const int glen   = tend - tstart;
    const int half0  = (glen + 1) >> 1;
    const int mylen  = cw ? glen - half0 : half0;  // <= 4
    const int mybase = tstart + (cw ? half0 : 0);
    const int gmax   = half0;                // loop bound (cw0 >= cw1 length)

    const unsigned psel = (quad < 2) ? 0x05040100u : 0x07060302u;
    const short* Kh = Kswz + (size_t)h * NTILE * 4096;
    const short* Vh = Vswz + (size_t)h * NTILE * 4096;
    unsigned* pw = p_lds[wave];
    const int swz = l16 & 7;
    const int so  = sw * 2048 + lane * 16;   // per-lane byte offset in tile/LDS

    // bias for this block's <=8 tiles: one value per thread
    {
        const int tt = tid >> 6, kk = tid & 63;
        if (tstart + tt < tend)
            bias_lds[tid] = Bias[(size_t)h * S_LEN + (tstart + tt) * K_TILE + kk];
    }

    // Q A-frags for 2 strips of this wave's 32 rows, scaled by 0.125*log2(e)
    bf16x8 qfrag[2][2];
    {
        const float* Qh = Qm + (size_t)h * S_LEN * D_DIM;
        #pragma unroll
        for (int s = 0; s < 2; ++s) {
            const int qrow = qblk * QT + sw * 32 + s * 16 + l16;
            #pragma unroll
            for (int t = 0; t < 2; ++t) {
                const float* src = Qh + (size_t)qrow * D_DIM + t * 32 + quad * 8;
                float4 a = *(const float4*)src;
                float4 b = *(const float4*)(src + 4);
                unsigned* qp = (unsigned*)&qfrag[s][t];
                qp[0] = pack2bf(a.x * SCL, a.y * SCL);
                qp[1] = pack2bf(a.z * SCL, a.w * SCL);
                qp[2] = pack2bf(b.x * SCL, b.y * SCL);
                qp[3] = pack2bf(b.z * SCL, b.w * SCL);
            }
        }
    }

    bf16x8 onesv;
    #pragma unroll
    for (int i = 0; i < 8; ++i) onesv[i] = (short)0x3F80;  // bf16 1.0

    f32x4 o_frag[2][4], l4[2];
    #pragma unroll
    for (int s = 0; s < 2; ++s) {
        #pragma unroll
        for (int cc = 0; cc < 4; ++cc) o_frag[s][cc] = (f32x4){0.f, 0.f, 0.f, 0.f};
        l4[s] = (f32x4){0.f, 0.f, 0.f, 0.f};
    }

    for (int i = 0; i < gmax; ++i) {
        __syncthreads();                     // prev compute done; bias visible
        if (i < mylen) {
            const int kt = mybase + i;
            const char* kg = (const char*)(Kh + (size_t)kt * 4096);
            const char* vg = (const char*)(Vh + (size_t)kt * 4096);
            char* kl = (char*)&k_lds[cw][0] + sw * 2048;
            char* vl = (char*)&v_lds[cw][0] + sw * 2048;
            load_lds16(kg + so,        kl);
            load_lds16(kg + so + 1024, kl + 1024);
            load_lds16(vg + so,        vl);
            load_lds16(vg + so + 1024, vl + 1024);
        }
        __syncthreads();                     // staged (vmcnt drained)
        if (i < mylen) {
            const int kt = mybase + i;
            const float* bm = &bias_lds[(kt - tstart) * K_TILE];
            const short* kb = &k_lds[cw][0];
            const short* vb = &v_lds[cw][0];

            // S(+bias) = bias_init + Q K^T
            f32x4 sv[2][4];
            __builtin_amdgcn_s_setprio(1);
            #pragma unroll
            for (int cc = 0; cc < 4; ++cc) {
                const float b = bm[cc * 16 + l16];
                const f32x4 binit = (f32x4){b, b, b, b};
                sv[0][cc] = binit;
                sv[1][cc] = binit;
                #pragma unroll
                for (int t = 0; t < 2; ++t) {
                    bf16x8 bfrag = *(const bf16x8*)&kb[(cc * 16 + l16) * 64 + (((t * 4 + quad) ^ swz) << 3)];
                    sv[0][cc] = __builtin_amdgcn_mfma_f32_16x16x32_bf16(qfrag[0][t], bfrag, sv[0][cc], 0, 0, 0);
                    sv[1][cc] = __builtin_amdgcn_mfma_f32_16x16x32_bf16(qfrag[1][t], bfrag, sv[1][cc], 0, 0, 0);
                }
            }
            __builtin_amdgcn_s_setprio(0);

            // p = exp2(s)
            #pragma unroll
            for (int s = 0; s < 2; ++s) {
                #pragma unroll
                for (int r = 0; r < 4; ++r) {
                    const float p0 = fexp2(sv[s][0][r]);
                    const float p1 = fexp2(sv[s][1][r]);
                    const float p2 = fexp2(sv[s][2][r]);
                    const float p3 = fexp2(sv[s][3][r]);
                    unsigned* pp = &pw[(s * 16 + quad * 4 + r) * PROWSTR + l16];
                    pp[0]  = pack2bf(p0, p1);
                    pp[16] = pack2bf(p2, p3);
                }
            }

            // O += P V ; l += P * ones
            #pragma unroll
            for (int t2 = 0; t2 < 2; ++t2) {
                bf16x8 pfrag[2];
                #pragma unroll
                for (int s = 0; s < 2; ++s) {
                    const unsigned* pr = &pw[(s * 16 + l16) * PROWSTR + t2 * 16 + (quad & 1) * 8];
                    uint4 w0 = *(const uint4*)(pr);
                    uint4 w1 = *(const uint4*)(pr + 4);
                    unsigned pf[4];
                    pf[0] = permb(w0.y, w0.x, psel);
                    pf[1] = permb(w0.w, w0.z, psel);
                    pf[2] = permb(w1.y, w1.x, psel);
                    pf[3] = permb(w1.w, w1.z, psel);
                    __builtin_memcpy(&pfrag[s], pf, 16);
                }
                __builtin_amdgcn_s_setprio(1);
                #pragma unroll
                for (int c2 = 0; c2 < 4; ++c2) {
                    bf16x8 vfrag = *(const bf16x8*)&vb[(c2 * 16 + l16) * 64 + (((t2 * 4 + quad) ^ swz) << 3)];
                    o_frag[0][c2] = __builtin_amdgcn_mfma_f32_16x16x32_bf16(pfrag[0], vfrag, o_frag[0][c2], 0, 0, 0);
                    o_frag[1][c2] = __builtin_amdgcn_mfma_f32_16x16x32_bf16(pfrag[1], vfrag, o_frag[1][c2], 0, 0, 0);
                }
                l4[0] = __builtin_amdgcn_mfma_f32_16x16x32_bf16(pfrag[0], onesv, l4[0], 0, 0, 0);
                l4[1] = __builtin_amdgcn_mfma_f32_16x16x32_bf16(pfrag[1], onesv, l4[1], 0, 0, 0);
                __builtin_amdgcn_s_setprio(0);
            }
        }
    }
    __syncthreads();   // all PV reads of p_lds done before cb reuse

    // ---- LDS merge of the two chunk-groups ----
    float* cb = (float*)p_lds;               // [4][32][68] floats (34.8 KB)
    if (cw == 1) {
        #pragma unroll
        for (int s = 0; s < 2; ++s) {
            #pragma unroll
            for (int c2 = 0; c2 < 4; ++c2) {
                #pragma unroll
                for (int r = 0; r < 4; ++r)
                    cb[(sw * 32 + s * 16 + quad * 4 + r) * 68 + c2 * 16 + l16] = o_frag[s][c2][r];
            }
            if (l16 == 0) {
                #pragma unroll
                for (int r = 0; r < 4; ++r)
                    l_cb[sw][s * 16 + quad * 4 + r] = l4[s][r];
            }
        }
    }
    __syncthreads();
    if (cw == 0) {
        if (np == 1) {
            // whole head in this block: direct normalized write
            float* Oh = Om + (size_t)h * S_LEN * D_DIM;
            const int qrow0 = qblk * QT + sw * 32;
            #pragma unroll
            for (int s = 0; s < 2; ++s) {
                #pragma unroll
                for (int r = 0; r < 4; ++r) {
                    const int rrow = s * 16 + quad * 4 + r;
                    const float inv = 1.0f / (l4[s][r] + l_cb[sw][rrow]);
                    const float* cr = &cb[(sw * 32 + rrow) * 68];
                    float* dst = Oh + (size_t)(qrow0 + rrow) * D_DIM + l16;
                    dst[0]  = (o_frag[s][0][r] + cr[0  + l16]) * inv;
                    dst[16] = (o_frag[s][1][r] + cr[16 + l16]) * inv;
                    dst[32] = (o_frag[s][2][r] + cr[32 + l16]) * inv;
                    dst[48] = (o_frag[s][3][r] + cr[48 + l16]) * inv;
                }
            }
        } else {
            // merged partial + l; slot = h*NPMAX + p (plain stores; the
            // dispatch boundary provides cross-XCD coherence)
            #pragma unroll
            for (int s = 0; s < 2; ++s) {
                const int g = qblk * 32 + sw * 8 + s * 4 + quad;
                const size_t gbase = (((size_t)h * NPMAX + p) * 512 + g);
                f32x4 lsum;
                #pragma unroll
                for (int r = 0; r < 4; ++r)
                    lsum[r] = l4[s][r] + l_cb[sw][s * 16 + quad * 4 + r];
                #pragma unroll
                for (int c2 = 0; c2 < 4; ++c2) {
                    f32x4 ov;
                    #pragma unroll
                    for (int r = 0; r < 4; ++r)
                        ov[r] = o_frag[s][c2][r] + cb[(sw * 32 + s * 16 + quad * 4 + r) * 68 + c2 * 16 + l16];
                    *(f32x4*)(Opart + (gbase * 64 + c2 * 16 + l16) * 4) = ov;
                }
                if (l16 == 0) *(f32x4*)(lp + gbase * 4) = lsum;
            }
        }
    }
}

__global__ __launch_bounds__(256)
void attn_combine_kernel(const float* __restrict__ Opart, const float* __restrict__ lp,
                         float* __restrict__ Om)
{
    const int t   = blockIdx.x * 256 + threadIdx.x;   // H*512*64 threads
    const int col = t & 63;
    const int g   = (t >> 6) & 511;
    const int h   = t >> 15;

    const int np = head_np(h);
    if (np == 1) return;                              // written directly by main

    f32x4 acc = (f32x4){0.f, 0.f, 0.f, 0.f};
    f32x4 den = (f32x4){0.f, 0.f, 0.f, 0.f};
    for (int c = 0; c < np; ++c) {
        const size_t gbase = (((size_t)h * NPMAX + c) * 512 + g);
        den += *(const f32x4*)(lp + gbase * 4);
        acc += *(const f32x4*)(Opart + (gbase * 64 + col) * 4);
    }
    float* Oh = Om + (size_t)h * S_LEN * D_DIM;
    #pragma unroll
    for (int r = 0; r < 4; ++r)
        Oh[(size_t)(g * 4 + r) * 64 + col] = acc[r] / den[r];
}

extern "C" void kernel_launch(void* const* d_in, const int* in_sizes, int n_in,
                              void* d_out, int out_size, void* d_ws, size_t ws_size,
                              hipStream_t stream) {
    (void)in_sizes; (void)n_in; (void)out_size; (void)ws_size;
    const float* Q = (const float*)d_in[0];
    const float* K = (const float*)d_in[1];
    const float* V = (const float*)d_in[2];
    const void*  M = d_in[3];
    float* O = (float*)d_out;

    char* ws = (char*)d_ws;
    size_t off = 0;
    short* Kswz = (short*)(ws + off); off += (size_t)H_NUM * S_LEN * D_DIM * 2;            // 4 MB
    short* Vswz = (short*)(ws + off); off += (size_t)H_NUM * S_LEN * D_DIM * 2;            // 4 MB
    float* Bias = (float*)(ws + off); off += (size_t)H_NUM * S_LEN * 4;                    // 128 KB
    float* Opart = (float*)(ws + off); off += (size_t)H_NUM * NPMAX * 512 * 64 * 4 * 4;    // 33.5 MB
    float* lp   = (float*)(ws + off); off += (size_t)H_NUM * NPMAX * 512 * 4 * 4;          // 0.5 MB

    preprocess_kernel<<<dim3(NTILE, H_NUM), 256, 0, stream>>>(K, V, M, Kswz, Vswz, Bias);
    attn_main<<<dim3(QB, H_NUM, NPMAX), 512, 0, stream>>>(Q, Kswz, Vswz, Bias, O, Opart, lp);
    attn_combine_kernel<<<(H_NUM * 512 * 64) / 256, 256, 0, stream>>>(Opart, lp, O);
}